// Round 1
// baseline (528.548 us; speedup 1.0000x reference)
//
#include <hip/hip_runtime.h>

// LSTM: B=4096, T=512, IN=14, H=28, OUT=2, fp32.
// Mapping: lane = (batch, hidden j), j padded to 32 -> 2 batch elems / wave.
// Block = 256 threads = 8 batch elems; grid = 512 blocks (2 blocks/CU).
// Weights in VGPRs (168 floats/lane); x staged via LDS in 64-step chunks;
// h exchanged via double-buffered LDS row (float4 broadcast reads).

#define IN_F 14
#define HID 28
#define T_STEPS 512
#define BATCH 4096
#define OUT_N 2
#define NB 8       // batch elems per block
#define TC 64      // timestep chunk staged in LDS
#define BLOCK 256

__device__ __forceinline__ float sigmoid_fast(float x) {
    float e = __expf(-x);               // v_exp_f32 (overflow -> inf -> rcp -> 0, correct)
    return __builtin_amdgcn_rcpf(1.0f + e);
}

__device__ __forceinline__ float tanh_fast(float x) {
    float ax = fabsf(x);
    float e = __expf(-2.0f * ax);       // e in (0,1], no overflow
    float r = (1.0f - e) * __builtin_amdgcn_rcpf(1.0f + e);
    return copysignf(r, x);
}

__global__ __launch_bounds__(BLOCK, 2)
void lstm_kernel(const float* __restrict__ x,
                 const float* __restrict__ W_ih,
                 const float* __restrict__ W_hh,
                 const float* __restrict__ b_ih,
                 const float* __restrict__ b_hh,
                 const float* __restrict__ W_out,
                 const float* __restrict__ b_out,
                 float* __restrict__ out) {
    __shared__ float x_s[NB][TC][16];    // 14 used, padded to 16 for b128 alignment
    __shared__ float h_s[2][NB][32];     // double-buffered hidden state

    const int tid = threadIdx.x;
    const int lb  = tid >> 5;            // local batch 0..7
    const int j   = tid & 31;            // hidden index (28..31 idle)
    const bool active = (j < HID);
    const int jc = active ? j : (HID - 1);   // clamp for in-bounds weight loads
    const int b0 = blockIdx.x * NB;

    // ---- load per-lane weight rows into registers ----
    float wih[4][IN_F];
    float whh[4][HID];
    float bias[4];
    #pragma unroll
    for (int g = 0; g < 4; ++g) {
        const int row = g * HID + jc;    // PyTorch gate order i,f,g,o
        #pragma unroll
        for (int i = 0; i < IN_F; ++i) wih[g][i] = W_ih[row * IN_F + i];
        #pragma unroll
        for (int k = 0; k < HID; ++k) whh[g][k] = W_hh[row * HID + k];
        bias[g] = b_ih[row] + b_hh[row];
    }

    // ---- init hidden state ----
    h_s[0][lb][j] = 0.0f;
    float c = 0.0f;
    __syncthreads();

    int cur = 0;
    for (int t0 = 0; t0 < T_STEPS; t0 += TC) {
        // stage x[b0:b0+NB, t0:t0+TC, 0:14] into LDS (coalesced per-batch runs)
        for (int u = tid; u < NB * TC * IN_F; u += BLOCK) {
            int bb = u / (TC * IN_F);
            int r  = u - bb * (TC * IN_F);
            int tt = r / IN_F;
            int ii = r - tt * IN_F;
            x_s[bb][tt][ii] = x[((b0 + bb) * T_STEPS + t0) * IN_F + r];
        }
        __syncthreads();

        for (int tt = 0; tt < TC; ++tt) {
            float acc0 = bias[0], acc1 = bias[1], acc2 = bias[2], acc3 = bias[3];

            // input projection: 14 x-values (LDS broadcast), 56 FMAs
            const float* xr = &x_s[lb][tt][0];
            float4 xv;
            #pragma unroll
            for (int i4 = 0; i4 < 3; ++i4) {
                xv = *(const float4*)(xr + 4 * i4);
                acc0 = fmaf(wih[0][4*i4+0], xv.x, acc0);
                acc1 = fmaf(wih[1][4*i4+0], xv.x, acc1);
                acc2 = fmaf(wih[2][4*i4+0], xv.x, acc2);
                acc3 = fmaf(wih[3][4*i4+0], xv.x, acc3);
                acc0 = fmaf(wih[0][4*i4+1], xv.y, acc0);
                acc1 = fmaf(wih[1][4*i4+1], xv.y, acc1);
                acc2 = fmaf(wih[2][4*i4+1], xv.y, acc2);
                acc3 = fmaf(wih[3][4*i4+1], xv.y, acc3);
                acc0 = fmaf(wih[0][4*i4+2], xv.z, acc0);
                acc1 = fmaf(wih[1][4*i4+2], xv.z, acc1);
                acc2 = fmaf(wih[2][4*i4+2], xv.z, acc2);
                acc3 = fmaf(wih[3][4*i4+2], xv.z, acc3);
                acc0 = fmaf(wih[0][4*i4+3], xv.w, acc0);
                acc1 = fmaf(wih[1][4*i4+3], xv.w, acc1);
                acc2 = fmaf(wih[2][4*i4+3], xv.w, acc2);
                acc3 = fmaf(wih[3][4*i4+3], xv.w, acc3);
            }
            float2 xv3 = *(const float2*)(xr + 12);
            acc0 = fmaf(wih[0][12], xv3.x, acc0);
            acc1 = fmaf(wih[1][12], xv3.x, acc1);
            acc2 = fmaf(wih[2][12], xv3.x, acc2);
            acc3 = fmaf(wih[3][12], xv3.x, acc3);
            acc0 = fmaf(wih[0][13], xv3.y, acc0);
            acc1 = fmaf(wih[1][13], xv3.y, acc1);
            acc2 = fmaf(wih[2][13], xv3.y, acc2);
            acc3 = fmaf(wih[3][13], xv3.y, acc3);

            // recurrent matvec: 28 h-values (LDS broadcast float4), 112 FMAs
            const float* hr = &h_s[cur][lb][0];
            #pragma unroll
            for (int k4 = 0; k4 < 7; ++k4) {
                float4 hv = *(const float4*)(hr + 4 * k4);
                acc0 = fmaf(whh[0][4*k4+0], hv.x, acc0);
                acc1 = fmaf(whh[1][4*k4+0], hv.x, acc1);
                acc2 = fmaf(whh[2][4*k4+0], hv.x, acc2);
                acc3 = fmaf(whh[3][4*k4+0], hv.x, acc3);
                acc0 = fmaf(whh[0][4*k4+1], hv.y, acc0);
                acc1 = fmaf(whh[1][4*k4+1], hv.y, acc1);
                acc2 = fmaf(whh[2][4*k4+1], hv.y, acc2);
                acc3 = fmaf(whh[3][4*k4+1], hv.y, acc3);
                acc0 = fmaf(whh[0][4*k4+2], hv.z, acc0);
                acc1 = fmaf(whh[1][4*k4+2], hv.z, acc1);
                acc2 = fmaf(whh[2][4*k4+2], hv.z, acc2);
                acc3 = fmaf(whh[3][4*k4+2], hv.z, acc3);
                acc0 = fmaf(whh[0][4*k4+3], hv.w, acc0);
                acc1 = fmaf(whh[1][4*k4+3], hv.w, acc1);
                acc2 = fmaf(whh[2][4*k4+3], hv.w, acc2);
                acc3 = fmaf(whh[3][4*k4+3], hv.w, acc3);
            }

            // gate nonlinearities + state update (PyTorch order: i,f,g,o)
            float ig = sigmoid_fast(acc0);
            float fg = sigmoid_fast(acc1);
            float gg = tanh_fast(acc2);
            float og = sigmoid_fast(acc3);
            c = fmaf(fg, c, ig * gg);
            float h = og * tanh_fast(c);
            if (!active) h = 0.0f;

            h_s[cur ^ 1][lb][j] = h;
            __syncthreads();
            cur ^= 1;
        }
    }

    // ---- output projection: out[b, o] = h_T . W_out[o] + b_out[o] ----
    if (tid < NB * OUT_N) {
        const int o  = tid & 1;
        const int bb = tid >> 1;
        float s = b_out[o];
        const float* hr = &h_s[cur][bb][0];
        #pragma unroll
        for (int k = 0; k < HID; ++k) s = fmaf(hr[k], W_out[o * HID + k], s);
        out[(b0 + bb) * OUT_N + o] = s;
    }
}

extern "C" void kernel_launch(void* const* d_in, const int* in_sizes, int n_in,
                              void* d_out, int out_size, void* d_ws, size_t ws_size,
                              hipStream_t stream) {
    const float* x     = (const float*)d_in[0];
    const float* W_ih  = (const float*)d_in[1];
    const float* W_hh  = (const float*)d_in[2];
    const float* b_ih  = (const float*)d_in[3];
    const float* b_hh  = (const float*)d_in[4];
    const float* W_out = (const float*)d_in[5];
    const float* b_out = (const float*)d_in[6];
    float* out = (float*)d_out;

    lstm_kernel<<<BATCH / NB, BLOCK, 0, stream>>>(
        x, W_ih, W_hh, b_ih, b_hh, W_out, b_out, out);
}

// Round 2
// 508.194 us; speedup vs baseline: 1.0401x; 1.0401x over previous
//
#include <hip/hip_runtime.h>

// LSTM B=4096 T=512 IN=14 H=28 OUT=2, fp32 in/out, bf16 MFMA recurrence.
// Block = 16 batch, 4 waves = 4 gates (i,f,g,o). Per step:
//   phase A (per wave): A-frag = [h(28)|0(4)|x(14)|0(18)] bf16 rows from LDS,
//     4x mfma_f32_16x16x32_bf16 (2 N-tiles x 2 K-tiles), wave-uniform
//     sigmoid/tanh, sigma -> LDS.
//   phase B (all 256): gate combine, c in regs, h -> LDS (bf16 A-row + fp32
//     copy), repack x_{t+1} into A-rows. x staged fp32 in 32-step chunks.

#define T_STEPS 512
#define BATCH   4096
#define IN_F    14
#define HID     28
#define OUT_N   2
#define MB      16                 // batch per block
#define TC      32                 // x chunk (timesteps)
#define XPITCH  (TC * IN_F + 1)    // 449, breaks bank alignment
#define SPITCH  20                 // sigma row pitch (floats), 80B = 16B-aligned

typedef __attribute__((ext_vector_type(8))) short  short8;
typedef __attribute__((ext_vector_type(4))) float  float4v;

__device__ __forceinline__ unsigned short f2bf(float f) {
    union { float f; unsigned int u; } v; v.f = f;
    unsigned int r = (v.u + 0x7FFFu + ((v.u >> 16) & 1u)) >> 16;  // RNE
    return (unsigned short)r;
}

__device__ __forceinline__ float sigmoid_fast(float p) {
    float e = __expf(-p);                       // inf -> rcp -> 0, safe
    return __builtin_amdgcn_rcpf(1.0f + e);
}
__device__ __forceinline__ float tanh_fast(float p) {
    float e = __expf(-2.0f * p);                // tanh = 2*sigma(2p)-1
    float s = __builtin_amdgcn_rcpf(1.0f + e);
    return fmaf(2.0f, s, -1.0f);
}

__global__ __launch_bounds__(256, 1)
void lstm_mfma(const float* __restrict__ x,
               const float* __restrict__ W_ih,
               const float* __restrict__ W_hh,
               const float* __restrict__ b_ih,
               const float* __restrict__ b_hh,
               const float* __restrict__ W_out,
               const float* __restrict__ b_out,
               float* __restrict__ out) {
    // A-operand rows: cols 0..27 = h (bf16), 28..31 = 0, 32..45 = x_t, 46..63 = 0.
    // Row pitch 72 shorts = 144 B (16B-aligned for ds_read_b128).
    __shared__ __align__(16) short h_a[MB][72];
    __shared__ __align__(16) float sg[4 * HID * SPITCH];   // sigma[g][u][b], pitch 20
    __shared__ float xch[MB * XPITCH];                     // fp32 x chunk
    __shared__ float hfin[MB][HID + 1];                    // fp32 h for epilogue

    const int tid = threadIdx.x;
    const int g   = tid >> 6;         // wave = gate (0=i,1=f,2=g,3=o)
    const int l   = tid & 63;
    const int q   = l >> 4;           // k-group
    const int m   = l & 15;           // A-row (batch) / B-col base
    const int b0  = blockIdx.x * MB;

    // ---- B fragments (weights) + bias, resident in VGPRs ----
    // B[k][n]: lane holds k = q*8+j (within K-tile), n = ntile*16 + m.
    short8 bfrag[2][2];               // [ktile][ntile]
    float  biasf[2];
    #pragma unroll
    for (int nt = 0; nt < 2; ++nt) {
        const int n   = nt * 16 + m;
        const int row = g * HID + n;          // gate row in [0,112)
        const bool vr = (n < HID);
        biasf[nt] = vr ? (b_ih[row] + b_hh[row]) : 0.0f;
        #pragma unroll
        for (int kt = 0; kt < 2; ++kt) {
            short8 v;
            #pragma unroll
            for (int j = 0; j < 8; ++j) {
                const int k = q * 8 + j;      // 0..31 within tile
                float w = 0.0f;
                if (vr) {
                    if (kt == 0) { if (k < HID)  w = W_hh[row * HID + k]; }
                    else         { if (k < IN_F) w = W_ih[row * IN_F + k]; }
                }
                v[j] = (short)f2bf(w);
            }
            bfrag[kt][nt] = v;
        }
    }

    // ---- init: zero A rows (h0 = 0, pads = 0) ----
    for (int u = tid; u < MB * 72; u += 256) ((short*)h_a)[u] = 0;

    // stage chunk 0 (steps 0..31)
    {
        const float* src = x + (long)b0 * T_STEPS * IN_F;
        for (int u = tid; u < MB * TC * IN_F; u += 256) {
            int bb = u / (TC * IN_F);
            int r  = u - bb * (TC * IN_F);
            xch[bb * XPITCH + r] = src[(long)bb * T_STEPS * IN_F + r];
        }
    }
    __syncthreads();
    // repack x_0 into A rows
    {
        const int rb = tid & 15, ri = tid >> 4;
        if (ri < IN_F)
            h_a[rb][32 + ri] = (short)f2bf(xch[rb * XPITCH + ri]);
    }
    __syncthreads();

    // phase-B ownership: (u = pu / pu+16, b = pb); c-state in registers
    const int pb = tid & 15;
    const int pu = tid >> 4;          // 0..15
    float c0 = 0.0f, c1 = 0.0f;

    for (int t = 0; t < T_STEPS; ++t) {
        // prefetch next chunk (covers steps t+1..t+32); visible after barrier 1
        if (((t + 1) & (TC - 1)) == 0 && (t + 1) < T_STEPS) {
            const float* src = x + ((long)b0 * T_STEPS + (t + 1)) * IN_F;
            for (int u = tid; u < MB * TC * IN_F; u += 256) {
                int bb = u / (TC * IN_F);
                int r  = u - bb * (TC * IN_F);
                xch[bb * XPITCH + r] = src[(long)bb * T_STEPS * IN_F + r];
            }
        }

        // ---- phase A: gates = [h|x] @ Wcat^T + bias ----
        const short* arow = &h_a[m][0];
        short8 a0 = *(const short8*)(arow + q * 8);        // k 0..31 (h)
        short8 a1 = *(const short8*)(arow + 32 + q * 8);   // k 32..63 (x)
        float4v acc0 = {biasf[0], biasf[0], biasf[0], biasf[0]};
        float4v acc1 = {biasf[1], biasf[1], biasf[1], biasf[1]};
        acc0 = __builtin_amdgcn_mfma_f32_16x16x32_bf16(a0, bfrag[0][0], acc0, 0, 0, 0);
        acc0 = __builtin_amdgcn_mfma_f32_16x16x32_bf16(a1, bfrag[1][0], acc0, 0, 0, 0);
        acc1 = __builtin_amdgcn_mfma_f32_16x16x32_bf16(a0, bfrag[0][1], acc1, 0, 0, 0);
        acc1 = __builtin_amdgcn_mfma_f32_16x16x32_bf16(a1, bfrag[1][1], acc1, 0, 0, 0);

        // wave-uniform nonlinearity; C/D layout: col = m (unit), rows = q*4+r (batch)
        float4v s0v, s1v;
        if (g == 2) {
            #pragma unroll
            for (int r = 0; r < 4; ++r) { s0v[r] = tanh_fast(acc0[r]); s1v[r] = tanh_fast(acc1[r]); }
        } else {
            #pragma unroll
            for (int r = 0; r < 4; ++r) { s0v[r] = sigmoid_fast(acc0[r]); s1v[r] = sigmoid_fast(acc1[r]); }
        }
        // sigma[g][u][b]: 4 consecutive batches per lane -> one b128 store
        *(float4v*)&sg[(g * HID + m) * SPITCH + q * 4] = s0v;
        if (m + 16 < HID)
            *(float4v*)&sg[(g * HID + m + 16) * SPITCH + q * 4] = s1v;

        __syncthreads();   // barrier 1: sigma (and staged chunk) visible

        // ---- phase B: combine gates, update c, write h ----
        {
            // pass 0: u = pu
            float iv = sg[(0 * HID + pu) * SPITCH + pb];
            float fv = sg[(1 * HID + pu) * SPITCH + pb];
            float gv = sg[(2 * HID + pu) * SPITCH + pb];
            float ov = sg[(3 * HID + pu) * SPITCH + pb];
            c0 = fmaf(fv, c0, iv * gv);
            float h0 = ov * tanh_fast(c0);
            h_a[pb][pu]  = (short)f2bf(h0);
            hfin[pb][pu] = h0;
            // pass 1: u = pu + 16 (valid for pu < 12)
            if (pu < HID - 16) {
                const int u1 = pu + 16;
                float iv1 = sg[(0 * HID + u1) * SPITCH + pb];
                float fv1 = sg[(1 * HID + u1) * SPITCH + pb];
                float gv1 = sg[(2 * HID + u1) * SPITCH + pb];
                float ov1 = sg[(3 * HID + u1) * SPITCH + pb];
                c1 = fmaf(fv1, c1, iv1 * gv1);
                float h1 = ov1 * tanh_fast(c1);
                h_a[pb][u1]  = (short)f2bf(h1);
                hfin[pb][u1] = h1;
            }
            // repack x_{t+1} into A rows (cols 32..45)
            if (t + 1 < T_STEPS) {
                const int ri = tid >> 4, rb = tid & 15;
                if (ri < IN_F) {
                    const int tt1 = (t + 1) & (TC - 1);
                    h_a[rb][32 + ri] = (short)f2bf(xch[rb * XPITCH + tt1 * IN_F + ri]);
                }
            }
        }
        __syncthreads();   // barrier 2: h_t / x_{t+1} visible for next step
    }

    // ---- epilogue: out[b][o] = hfin[b] . W_out[o] + b_out[o] (fp32) ----
    if (tid < MB * OUT_N) {
        const int o  = tid & 1;
        const int bb = tid >> 1;
        float s = b_out[o];
        #pragma unroll
        for (int u = 0; u < HID; ++u)
            s = fmaf(hfin[bb][u], W_out[o * HID + u], s);
        out[(b0 + bb) * OUT_N + o] = s;
    }
}

extern "C" void kernel_launch(void* const* d_in, const int* in_sizes, int n_in,
                              void* d_out, int out_size, void* d_ws, size_t ws_size,
                              hipStream_t stream) {
    const float* x     = (const float*)d_in[0];
    const float* W_ih  = (const float*)d_in[1];
    const float* W_hh  = (const float*)d_in[2];
    const float* b_ih  = (const float*)d_in[3];
    const float* b_hh  = (const float*)d_in[4];
    const float* W_out = (const float*)d_in[5];
    const float* b_out = (const float*)d_in[6];
    float* out = (float*)d_out;

    lstm_mfma<<<BATCH / MB, 256, 0, stream>>>(
        x, W_ih, W_hh, b_ih, b_hh, W_out, b_out, out);
}

// Round 3
// 334.142 us; speedup vs baseline: 1.5818x; 1.5209x over previous
//
#include <hip/hip_runtime.h>

// LSTM B=4096 T=512 IN=14 H=28 OUT=2, fp32 in/out.
// Grid 512 x 256thr (MB=8 batch/block), __launch_bounds__(256,2) -> 2 blocks/CU
// so barrier stalls of one block hide under the other's compute.
// Per step:
//   phase A: wave g computes raw gate-g preacts via 4x mfma_f32_16x16x32_bf16
//            (A = [h(28)|pad | x(14)|pad] bf16 rows, B = weights in VGPRs,
//            bias in acc init), stores raw preacts (rows 0..7 only).
//   phase B: 224 threads, one (b,u) element each: merged-rcp gates
//            (5 exp + 2 rcp), c in thread registers, h -> bf16 A-row + f32 copy.
// x is pre-converted to bf16 A-layout per 16-step chunk (double-buffered);
// next chunk's global loads are held in 7 VGPRs across the chunk (latency hidden).

#define T_STEPS 512
#define BATCH   4096
#define IN_F    14
#define HID     28
#define OUT_N   2
#define MB      8                  // batch per block
#define TC      16                 // timesteps per x chunk
#define NCHUNK  (T_STEPS / TC)     // 32
#define HPITCH  40                 // shorts per A-row (80 B, 16B-aligned, 2-way banks)
#define PPITCH  20                 // floats per preact row (80 B, 16B-aligned)
#define XREGS   ((MB * TC * IN_F) / 256)   // 7 fp32 per thread per chunk

typedef __attribute__((ext_vector_type(8))) short  short8;
typedef __attribute__((ext_vector_type(4))) float  float4v;

#define L1 1.4426950408889634f
#define L2 2.8853900817779268f

__device__ __forceinline__ unsigned short f2bf(float f) {
    union { float f; unsigned int u; } v; v.f = f;
    unsigned int r = (v.u + 0x7FFFu + ((v.u >> 16) & 1u)) >> 16;  // RNE
    return (unsigned short)r;
}

__global__ __launch_bounds__(256, 2)
void lstm_mfma2(const float* __restrict__ x,
                const float* __restrict__ W_ih,
                const float* __restrict__ W_hh,
                const float* __restrict__ b_ih,
                const float* __restrict__ b_hh,
                const float* __restrict__ W_out,
                const float* __restrict__ b_out,
                float* __restrict__ out) {
    __shared__ __align__(16) short h_a[MB][HPITCH];            // bf16 h rows (cols 0..27; 28..31 = 0)
    __shared__ __align__(16) short x_a[2][TC][MB][HPITCH];     // bf16 x rows (cols 0..13; 14..31 = 0)
    __shared__ __align__(16) float pre[4 * HID * PPITCH];      // raw preacts [g][u][b]
    __shared__ float hfin[MB][HID];                            // f32 h for epilogue

    const int tid = threadIdx.x;
    const int wg  = tid >> 6;        // wave = gate (0=i,1=f,2=g,3=o)
    const int l   = tid & 63;
    const int q   = l >> 4;
    const int m   = l & 15;
    const int mr  = m & 7;           // A-row (batch), rows 8..15 duplicate 0..7
    const int b0  = blockIdx.x * MB;

    // ---- weights -> VGPR B-fragments; bias for acc init ----
    short8 bfrag[2][2];              // [ktile][ntile]
    float  biasf[2];
    #pragma unroll
    for (int nt = 0; nt < 2; ++nt) {
        const int n   = nt * 16 + m;
        const bool vr = (n < HID);
        const int row = wg * HID + (vr ? n : 0);
        biasf[nt] = vr ? (b_ih[row] + b_hh[row]) : 0.0f;
        #pragma unroll
        for (int kt = 0; kt < 2; ++kt) {
            short8 v;
            #pragma unroll
            for (int j = 0; j < 8; ++j) {
                const int k = q * 8 + j;
                float w = 0.0f;
                if (vr) {
                    if (kt == 0) { if (k < HID)  w = W_hh[row * HID + k]; }
                    else         { if (k < IN_F) w = W_ih[row * IN_F + k]; }
                }
                v[j] = (short)f2bf(w);
            }
            bfrag[kt][nt] = v;
        }
    }

    // ---- zero h0 and x pads ----
    for (int u = tid; u < MB * HPITCH; u += 256) ((short*)h_a)[u] = 0;
    for (int u = tid; u < 2 * TC * MB * HPITCH; u += 256) ((short*)x_a)[u] = 0;

    // ---- prefetch chunk 0 into registers ----
    const float* xbase = x + (long)b0 * T_STEPS * IN_F;
    float xr[XREGS];
    #pragma unroll
    for (int k = 0; k < XREGS; ++k) {
        const int u  = tid + 256 * k;
        const int bb = u / (TC * IN_F);
        const int r  = u - bb * (TC * IN_F);
        xr[k] = xbase[(long)bb * T_STEPS * IN_F + r];
    }
    __syncthreads();   // zero-init visible

    // phase-B element ownership: (b = pb, u = pu), 224 active threads
    const int pb = tid & 7;
    const int pu = tid >> 3;         // 0..31
    const bool bact = (pu < HID);
    float c = 0.0f;

    for (int ch = 0; ch < NCHUNK; ++ch) {
        const int buf = ch & 1;
        // convert held registers -> bf16 A-layout for this chunk
        #pragma unroll
        for (int k = 0; k < XREGS; ++k) {
            const int u  = tid + 256 * k;
            const int bb = u / (TC * IN_F);
            const int r  = u - bb * (TC * IN_F);
            const int t  = r / IN_F;
            const int f  = r - t * IN_F;
            x_a[buf][t][bb][f] = (short)f2bf(xr[k]);
        }
        // issue next chunk's global loads (consumed NCHUNK steps later)
        if (ch + 1 < NCHUNK) {
            #pragma unroll
            for (int k = 0; k < XREGS; ++k) {
                const int u  = tid + 256 * k;
                const int bb = u / (TC * IN_F);
                const int r  = u - bb * (TC * IN_F);
                xr[k] = xbase[(long)bb * T_STEPS * IN_F + (ch + 1) * TC * IN_F + r];
            }
        }
        __syncthreads();   // x_a[buf] visible

        for (int tt = 0; tt < TC; ++tt) {
            // ---- phase A: raw gate preacts via MFMA ----
            short8 a0 = *(const short8*)&h_a[mr][q * 8];
            short8 a1 = *(const short8*)&x_a[buf][tt][mr][q * 8];
            float4v acc0 = {biasf[0], biasf[0], biasf[0], biasf[0]};
            float4v acc1 = {biasf[1], biasf[1], biasf[1], biasf[1]};
            acc0 = __builtin_amdgcn_mfma_f32_16x16x32_bf16(a0, bfrag[0][0], acc0, 0, 0, 0);
            acc0 = __builtin_amdgcn_mfma_f32_16x16x32_bf16(a1, bfrag[1][0], acc0, 0, 0, 0);
            acc1 = __builtin_amdgcn_mfma_f32_16x16x32_bf16(a0, bfrag[0][1], acc1, 0, 0, 0);
            acc1 = __builtin_amdgcn_mfma_f32_16x16x32_bf16(a1, bfrag[1][1], acc1, 0, 0, 0);
            // C/D: col = m (unit), row = q*4+r (batch); only rows 0..7 valid
            if (q < 2) {
                *(float4v*)&pre[(wg * HID + m) * PPITCH + q * 4] = acc0;
                if (m < HID - 16)
                    *(float4v*)&pre[(wg * HID + m + 16) * PPITCH + q * 4] = acc1;
            }
            __syncthreads();   // preacts visible

            // ---- phase B: one element per thread ----
            if (bact) {
                float pi = pre[(0 * HID + pu) * PPITCH + pb];
                float pf = pre[(1 * HID + pu) * PPITCH + pb];
                float pg = pre[(2 * HID + pu) * PPITCH + pb];
                float po = pre[(3 * HID + pu) * PPITCH + pb];
                float ei = __builtin_amdgcn_exp2f(pi * (-L1));
                float ef = __builtin_amdgcn_exp2f(pf * (-L1));
                float eg = __builtin_amdgcn_exp2f(pg * (-L2));
                float eo = __builtin_amdgcn_exp2f(po * (-L1));
                float av = 1.0f + ei, bv = 1.0f + ef, dv = 1.0f + eg, vv = 1.0f + eo;
                float pd  = av * dv;
                float pqv = pd * bv;
                float rv  = __builtin_amdgcn_rcpf(pqv);
                float sfv = pd * rv;                       // sigma(f)
                float igv = (1.0f - eg) * bv * rv;         // sigma(i)*tanh(g)
                c = fmaf(sfv, c, igv);
                float ec = __builtin_amdgcn_exp2f(c * (-L2));
                float wv = 1.0f + ec;
                float r2 = __builtin_amdgcn_rcpf(vv * wv);
                float h  = (1.0f - ec) * r2;               // sigma(o)*tanh(c)
                h_a[pb][pu]  = (short)f2bf(h);
                hfin[pb][pu] = h;
            }
            __syncthreads();   // h_t visible for next step
        }
    }

    // ---- epilogue: out[b][o] = hfin[b] . W_out[o] + b_out[o] ----
    if (tid < MB * OUT_N) {
        const int o  = tid & 1;
        const int bb = tid >> 1;
        float s = b_out[o];
        #pragma unroll
        for (int u = 0; u < HID; ++u)
            s = fmaf(hfin[bb][u], W_out[o * HID + u], s);
        out[(b0 + bb) * OUT_N + o] = s;
    }
}

extern "C" void kernel_launch(void* const* d_in, const int* in_sizes, int n_in,
                              void* d_out, int out_size, void* d_ws, size_t ws_size,
                              hipStream_t stream) {
    const float* x     = (const float*)d_in[0];
    const float* W_ih  = (const float*)d_in[1];
    const float* W_hh  = (const float*)d_in[2];
    const float* b_ih  = (const float*)d_in[3];
    const float* b_hh  = (const float*)d_in[4];
    const float* W_out = (const float*)d_in[5];
    const float* b_out = (const float*)d_in[6];
    float* out = (float*)d_out;

    lstm_mfma2<<<BATCH / MB, 256, 0, stream>>>(
        x, W_ih, W_hh, b_ih, b_hh, W_out, b_out, out);
}